// Round 5
// baseline (20994.688 us; speedup 1.0000x reference)
//
#include <hip/hip_runtime.h>
#include <math.h>

// Decoder: B=1024, Z=256, TDIM=512, CF=1024, A=64, R=128, T=64
// R5: (1) all 3 recurrent gate GEMMs batched in ONE z=3 launch (768 blocks = 3/CU;
//     r/t GEMMs depend only on prev-step hr/ht, not current act index);
//     (2) act/res heads fused to single kernels (LDS row staging + packed-transposed
//     weights, wave softmax/argmax) — no partial-matrix HBM round trip.
//     fp16 2-way-split MFMA GEMMs as R4 (verified: absmax at bf16 output floor).

__device__ __forceinline__ float sigf(float x) { return 1.0f / (1.0f + expf(-x)); }

typedef __attribute__((ext_vector_type(8))) _Float16 f16x8;
typedef __attribute__((ext_vector_type(4))) float f32x4;

__device__ __forceinline__ void split_f16(float x, unsigned short& hi, unsigned short& lo) {
    _Float16 h = (_Float16)x;                   // RNE f32->f16
    float r = (x - (float)h) * 2048.0f;         // exact
    _Float16 l = (_Float16)r;
    hi = __builtin_bit_cast(unsigned short, h);
    lo = __builtin_bit_cast(unsigned short, l);
}

// ---------------- fp16-split MFMA GEMM: C = A[M,K] @ W[N,K]^T ----------------
// 128x128 tile, BK=32, 256 threads = 4 waves (2x2), each wave 64x64 (4x4 frags of 16x16).
struct SPH {
    const unsigned short* Ah; const unsigned short* Al;
    const unsigned short* Wh; const unsigned short* Wl;
    float* C;
};

__global__ __launch_bounds__(256) void gemm_f16s(
    SPH p0, SPH p1, SPH p2, int K, int N, const float* __restrict__ bias, int relu)
{
    SPH P = blockIdx.z == 0 ? p0 : (blockIdx.z == 1 ? p1 : p2);
    __shared__ unsigned short lds[16384];   // 32KB: Ah[0:4096) Al[4096) Wh[8192) Wl[12288)
    const int tid = threadIdx.x;
    const int wave = tid >> 6, lane = tid & 63;
    const int wm = wave >> 1, wn = wave & 1;
    const int lrow = lane & 15, lq = lane >> 4;
    const int m0 = blockIdx.x * 128, n0 = blockIdx.y * 128;

    f32x4 acch[4][4], accl[4][4];
#pragma unroll
    for (int i = 0; i < 4; i++)
#pragma unroll
        for (int j = 0; j < 4; j++) {
            acch[i][j] = (f32x4){0.f, 0.f, 0.f, 0.f};
            accl[i][j] = (f32x4){0.f, 0.f, 0.f, 0.f};
        }

    for (int k0 = 0; k0 < K; k0 += 32) {
        __syncthreads();
#pragma unroll
        for (int ss = 0; ss < 2; ss++) {
            int s = wave * 2 + ss;
            int mrow = m0 + s * 16 + lrow;
            int nrow = n0 + s * 16 + lrow;
            int k = k0 + lq * 8;
            __builtin_amdgcn_global_load_lds(
                (const __attribute__((address_space(1))) void*)(P.Ah + (size_t)mrow * K + k),
                (__attribute__((address_space(3))) void*)&lds[s * 512], 16, 0, 0);
            __builtin_amdgcn_global_load_lds(
                (const __attribute__((address_space(1))) void*)(P.Al + (size_t)mrow * K + k),
                (__attribute__((address_space(3))) void*)&lds[4096 + s * 512], 16, 0, 0);
            __builtin_amdgcn_global_load_lds(
                (const __attribute__((address_space(1))) void*)(P.Wh + (size_t)nrow * K + k),
                (__attribute__((address_space(3))) void*)&lds[8192 + s * 512], 16, 0, 0);
            __builtin_amdgcn_global_load_lds(
                (const __attribute__((address_space(1))) void*)(P.Wl + (size_t)nrow * K + k),
                (__attribute__((address_space(3))) void*)&lds[12288 + s * 512], 16, 0, 0);
        }
        __syncthreads();

        f16x8 ah[4], al[4], bh[4], bl[4];
#pragma unroll
        for (int mi = 0; mi < 4; mi++) {
            ah[mi] = *(const f16x8*)&lds[(wm * 4 + mi) * 512 + lane * 8];
            al[mi] = *(const f16x8*)&lds[4096 + (wm * 4 + mi) * 512 + lane * 8];
        }
#pragma unroll
        for (int ni = 0; ni < 4; ni++) {
            bh[ni] = *(const f16x8*)&lds[8192 + (wn * 4 + ni) * 512 + lane * 8];
            bl[ni] = *(const f16x8*)&lds[12288 + (wn * 4 + ni) * 512 + lane * 8];
        }
#pragma unroll
        for (int mi = 0; mi < 4; mi++)
#pragma unroll
            for (int ni = 0; ni < 4; ni++) {
                acch[mi][ni] = __builtin_amdgcn_mfma_f32_16x16x32_f16(ah[mi], bh[ni], acch[mi][ni], 0, 0, 0);
                accl[mi][ni] = __builtin_amdgcn_mfma_f32_16x16x32_f16(al[mi], bh[ni], accl[mi][ni], 0, 0, 0);
                accl[mi][ni] = __builtin_amdgcn_mfma_f32_16x16x32_f16(ah[mi], bl[ni], accl[mi][ni], 0, 0, 0);
            }
    }

    const float s_lo = 1.0f / 2048.0f;
#pragma unroll
    for (int mi = 0; mi < 4; mi++)
#pragma unroll
        for (int ni = 0; ni < 4; ni++) {
            int row = m0 + wm * 64 + mi * 16 + lq * 4;
            int col = n0 + wn * 64 + ni * 16 + lrow;
            float bv = bias ? bias[col] : 0.0f;
#pragma unroll
            for (int r = 0; r < 4; r++) {
                float v = acch[mi][ni][r] + accl[mi][ni][r] * s_lo + bv;
                if (relu) v = fmaxf(v, 0.0f);
                P.C[(size_t)(row + r) * N + col] = v;
            }
        }
}

// ---------------- fp32 GEMM (setup only) ----------------
__global__ __launch_bounds__(256) void gemm_f32(
    const float* __restrict__ A0, const float* __restrict__ W0, float* __restrict__ C0,
    const float* __restrict__ A1, const float* __restrict__ W1, float* __restrict__ C1,
    int lda, int ldw, int ldc, int K, const float* __restrict__ bias, int relu)
{
    const float* Ap = blockIdx.z ? A1 : A0;
    const float* Wp = blockIdx.z ? W1 : W0;
    float*       Cp = blockIdx.z ? C1 : C0;
    __shared__ float As[16][128];
    __shared__ float Bs[16][64];
    const int tid = threadIdx.x;
    const int m0 = blockIdx.x * 128, n0 = blockIdx.y * 64;
    const int tx = tid & 7, ty = tid >> 3;
    const bool wal = (ldw & 3) == 0;
    float acc[4][8];
#pragma unroll
    for (int i = 0; i < 4; i++)
#pragma unroll
        for (int j = 0; j < 8; j++) acc[i][j] = 0.0f;

    for (int k0 = 0; k0 < K; k0 += 16) {
        __syncthreads();
#pragma unroll
        for (int q = 0; q < 2; q++) {
            int t2 = tid + q * 256;
            int kq = t2 & 3, m = t2 >> 2;
            float4 v = *(const float4*)(Ap + (size_t)(m0 + m) * lda + k0 + kq * 4);
            As[kq * 4 + 0][m] = v.x; As[kq * 4 + 1][m] = v.y;
            As[kq * 4 + 2][m] = v.z; As[kq * 4 + 3][m] = v.w;
        }
        {
            int kq = tid & 3, n = tid >> 2;
            const float* src = Wp + (size_t)(n0 + n) * ldw + k0 + kq * 4;
            float4 v;
            if (wal) v = *(const float4*)src;
            else { v.x = src[0]; v.y = src[1]; v.z = src[2]; v.w = src[3]; }
            Bs[kq * 4 + 0][n] = v.x; Bs[kq * 4 + 1][n] = v.y;
            Bs[kq * 4 + 2][n] = v.z; Bs[kq * 4 + 3][n] = v.w;
        }
        __syncthreads();
#pragma unroll
        for (int k = 0; k < 16; k++) {
            float a4[4], b8[8];
            *(float4*)a4 = *(const float4*)&As[k][ty * 4];
            *(float4*)(b8) = *(const float4*)&Bs[k][tx * 8];
            *(float4*)(b8 + 4) = *(const float4*)&Bs[k][tx * 8 + 4];
#pragma unroll
            for (int i = 0; i < 4; i++)
#pragma unroll
                for (int j = 0; j < 8; j++) acc[i][j] = fmaf(a4[i], b8[j], acc[i][j]);
        }
    }
#pragma unroll
    for (int i = 0; i < 4; i++) {
        int m = m0 + ty * 4 + i;
        float vb[8];
#pragma unroll
        for (int j = 0; j < 8; j++) {
            float v = acc[i][j];
            if (bias) v += bias[n0 + tx * 8 + j];
            if (relu) v = fmaxf(v, 0.0f);
            vb[j] = v;
        }
        float* dst = Cp + (size_t)m * ldc + n0 + tx * 8;
        *(float4*)dst = make_float4(vb[0], vb[1], vb[2], vb[3]);
        *(float4*)(dst + 4) = make_float4(vb[4], vb[5], vb[6], vb[7]);
    }
}

// ------------- fused act head: logits -> softmax + argmax (one launch) -------------
// grid 256 x 256 thr. Block handles 4 batch rows (one wave per row). wT4 packed:
// wT4[((k>>2)*64 + col)*4 + (k&3)] = W[col][k]  -> lane reads coalesced float4.
__global__ __launch_bounds__(256) void act_head(
    const float* __restrict__ ha, const float* __restrict__ wT4, const float* __restrict__ bias,
    float* __restrict__ out_probs, int t, int* __restrict__ aidx)
{
    __shared__ float As[4][1024];
    const int tid = threadIdx.x;
    const int b0 = blockIdx.x * 4;
#pragma unroll
    for (int q = 0; q < 4; q++) {
        int j = tid + q * 256;            // float4 index in [0,1024)
        int row = j >> 8, kk = j & 255;
        ((float4*)As[row])[kk] = *(const float4*)(ha + (size_t)(b0 + row) * 1024 + kk * 4);
    }
    __syncthreads();
    const int lane = tid & 63, w = tid >> 6;
    const int b = b0 + w;
    float acc = bias[lane];
    const float4* arow = (const float4*)As[w];
#pragma unroll 4
    for (int k4 = 0; k4 < 256; k4++) {
        float4 a4 = arow[k4];
        float4 w4 = *(const float4*)(wT4 + ((size_t)k4 * 64 + lane) * 4);
        acc += a4.x * w4.x + a4.y * w4.y + a4.z * w4.z + a4.w * w4.w;
    }
    float v = acc; int idx = lane;
#pragma unroll
    for (int off = 32; off; off >>= 1) {
        float ov = __shfl_xor(v, off);
        int   oi = __shfl_xor(idx, off);
        if (ov > v || (ov == v && oi < idx)) { v = ov; idx = oi; }
    }
    float e = expf(acc - v);
    float s = e;
#pragma unroll
    for (int off = 32; off; off >>= 1) s += __shfl_xor(s, off);
    out_probs[((size_t)b * 64 + t) * 64 + lane] = e / s;
    if (lane == 0) aidx[b] = idx;
}

// ------------- fused res head (128 cols: 2 per lane) -------------
__global__ __launch_bounds__(256) void res_head(
    const float* __restrict__ hr, const float* __restrict__ wT4, const float* __restrict__ bias,
    float* __restrict__ out_probs, int t, int* __restrict__ ridx)
{
    __shared__ float As[4][1024];
    const int tid = threadIdx.x;
    const int b0 = blockIdx.x * 4;
#pragma unroll
    for (int q = 0; q < 4; q++) {
        int j = tid + q * 256;
        int row = j >> 8, kk = j & 255;
        ((float4*)As[row])[kk] = *(const float4*)(hr + (size_t)(b0 + row) * 1024 + kk * 4);
    }
    __syncthreads();
    const int lane = tid & 63, w = tid >> 6;
    const int b = b0 + w;
    float acc0 = bias[lane], acc1 = bias[lane + 64];
    const float4* arow = (const float4*)As[w];
#pragma unroll 4
    for (int k4 = 0; k4 < 256; k4++) {
        float4 a4 = arow[k4];
        float4 w40 = *(const float4*)(wT4 + ((size_t)k4 * 128 + lane) * 4);
        float4 w41 = *(const float4*)(wT4 + ((size_t)k4 * 128 + lane + 64) * 4);
        acc0 += a4.x * w40.x + a4.y * w40.y + a4.z * w40.z + a4.w * w40.w;
        acc1 += a4.x * w41.x + a4.y * w41.y + a4.z * w41.z + a4.w * w41.w;
    }
    float v = acc0; int idx = lane;
    if (acc1 > v) { v = acc1; idx = lane + 64; }
#pragma unroll
    for (int off = 32; off; off >>= 1) {
        float ov = __shfl_xor(v, off);
        int   oi = __shfl_xor(idx, off);
        if (ov > v || (ov == v && oi < idx)) { v = ov; idx = oi; }
    }
    float e0 = expf(acc0 - v), e1 = expf(acc1 - v);
    float s = e0 + e1;
#pragma unroll
    for (int off = 32; off; off >>= 1) s += __shfl_xor(s, off);
    float* dst = out_probs + ((size_t)b * 64 + t) * 128;
    dst[lane] = e0 / s; dst[lane + 64] = e1 / s;
    if (lane == 0) ridx[b] = idx;
}

// ------------- pointwise LSTM (cell a) -------------
__global__ __launch_bounds__(256) void lstm_pw_a(
    const float* __restrict__ gates, const float* __restrict__ base,
    const float* __restrict__ E1, const int* __restrict__ idx1,
    float* __restrict__ h, float* __restrict__ c,
    unsigned short* __restrict__ h_hi, unsigned short* __restrict__ h_lo)
{
    int i = blockIdx.x * 256 + threadIdx.x;
    int b = i >> 10, j = i & 1023;
    size_t r = (size_t)b * 4096 + j;
    const float* e1 = E1 + (size_t)idx1[b] * 4096 + j;
    float gi = gates[r]        + base[r]        + e1[0];
    float gf = gates[r + 1024] + base[r + 1024] + e1[1024];
    float gg = gates[r + 2048] + base[r + 2048] + e1[2048];
    float go = gates[r + 3072] + base[r + 3072] + e1[3072];
    float cn = sigf(gf) * c[i] + sigf(gi) * tanhf(gg);
    c[i] = cn;
    float hn = sigf(go) * tanhf(cn);
    h[i] = hn;
    split_f16(hn, h_hi[i], h_lo[i]);
}

// ------------- fused pointwise LSTM for cells r and t -------------
__global__ __launch_bounds__(256) void lstm_pw_rt(
    const float* __restrict__ gates_r, const float* __restrict__ base_r,
    const float* __restrict__ Er_a, const float* __restrict__ Er_r,
    const int* __restrict__ aidx, const int* __restrict__ ridx,
    float* __restrict__ hr, float* __restrict__ cr,
    unsigned short* __restrict__ hr0, unsigned short* __restrict__ hr1,
    const float* __restrict__ gates_t, const float* __restrict__ base_t,
    const float* __restrict__ Et_a, const float* __restrict__ wtts, const float* __restrict__ tsv,
    float* __restrict__ ht, float* __restrict__ ct,
    unsigned short* __restrict__ ht0, unsigned short* __restrict__ ht1)
{
    int blk = blockIdx.x;
    int i = (blk & 4095) * 256 + threadIdx.x;
    int b = i >> 10, j = i & 1023;
    size_t r = (size_t)b * 4096 + j;
    if (blk < 4096) {
        const float* e1 = Er_a + (size_t)aidx[b] * 4096 + j;
        const float* e2 = Er_r + (size_t)ridx[b] * 4096 + j;
        float gi = gates_r[r]        + base_r[r]        + e1[0]    + e2[0];
        float gf = gates_r[r + 1024] + base_r[r + 1024] + e1[1024] + e2[1024];
        float gg = gates_r[r + 2048] + base_r[r + 2048] + e1[2048] + e2[2048];
        float go = gates_r[r + 3072] + base_r[r + 3072] + e1[3072] + e2[3072];
        float cn = sigf(gf) * cr[i] + sigf(gi) * tanhf(gg);
        cr[i] = cn;
        float hn = sigf(go) * tanhf(cn);
        hr[i] = hn;
        split_f16(hn, hr0[i], hr1[i]);
    } else {
        const float* e1 = Et_a + (size_t)aidx[b] * 4096 + j;
        float tv = tsv[b];
        float gi = gates_t[r]        + base_t[r]        + e1[0];
        float gf = gates_t[r + 1024] + base_t[r + 1024] + e1[1024];
        float gg = gates_t[r + 2048] + base_t[r + 2048] + e1[2048];
        float go = gates_t[r + 3072] + base_t[r + 3072] + e1[3072];
        gi = fmaf(tv, wtts[j], gi);        gf = fmaf(tv, wtts[j + 1024], gf);
        gg = fmaf(tv, wtts[j + 2048], gg); go = fmaf(tv, wtts[j + 3072], go);
        float cn = sigf(gf) * ct[i] + sigf(gi) * tanhf(gg);
        ct[i] = cn;
        float hn = sigf(go) * tanhf(cn);
        ht[i] = hn;
        split_f16(hn, ht0[i], ht1[i]);
    }
}

// ------------- ts final -------------
__global__ __launch_bounds__(256) void ts_final(
    const float* __restrict__ u, const float* __restrict__ w2, const float* __restrict__ b2,
    float* __restrict__ out_ts, int t, float* __restrict__ tsv)
{
    int lane = threadIdx.x & 63;
    int b = blockIdx.x * 4 + (threadIdx.x >> 6);
    const float* ur = u + (size_t)b * 512;
    float s = 0.0f;
#pragma unroll
    for (int q = 0; q < 8; q++) s = fmaf(ur[lane + q * 64], w2[lane + q * 64], s);
#pragma unroll
    for (int off = 32; off; off >>= 1) s += __shfl_xor(s, off);
    if (lane == 0) {
        float r = s + b2[0];
        out_ts[b * 64 + t] = r;
        tsv[b] = r;
    }
}

// ------------- setup kernels -------------
__global__ void extract_cols(const float* __restrict__ Wih, int ldw, int col0, int ncols,
                             float* __restrict__ E)
{
    int i = blockIdx.x * 256 + threadIdx.x;
    if (i >= ncols * 4096) return;
    int c = i % ncols, j = i / ncols;
    E[(size_t)c * 4096 + j] = Wih[(size_t)j * ldw + col0 + c];
}

__global__ void split_mat_h(const float* __restrict__ X,
                            unsigned short* __restrict__ hi, unsigned short* __restrict__ lo, int n)
{
    int i = blockIdx.x * 256 + threadIdx.x;
    if (i >= n) return;
    split_f16(X[i], hi[i], lo[i]);
}

// pack-transpose: out[((k>>2)*C + c)*4 + (k&3)] = W[c*K + k]
__global__ void transpose_pack(const float* __restrict__ W, int K, int C, float* __restrict__ out)
{
    int i = blockIdx.x * 256 + threadIdx.x;
    if (i >= C * K) return;
    int c = i / K, k = i - c * K;
    out[(((size_t)(k >> 2) * C + c) << 2) + (k & 3)] = W[i];
}

__global__ void init_state(float* __restrict__ hc, unsigned int* __restrict__ hilo,
                           float* __restrict__ tsv, int* __restrict__ aidx, int* __restrict__ ridx)
{
    int i = blockIdx.x * 256 + threadIdx.x;
    if (i < 6 * 1024 * 1024) hc[i] = 0.0f;
    if (i < 3 * 1024 * 1024) hilo[i] = 0u;          // 6M ushort of split state
    if (i < 1024) { tsv[i] = 0.0f; aidx[i] = 63; ridx[i] = 127; }
}

extern "C" void kernel_launch(void* const* d_in, const int* in_sizes, int n_in,
                              void* d_out, int out_size, void* d_ws, size_t ws_size,
                              hipStream_t stream)
{
    const float* z       = (const float*)d_in[0];
    const float* z2t_w   = (const float*)d_in[1];
    const float* z2t_b   = (const float*)d_in[2];
    const float* Wih_a   = (const float*)d_in[3];
    const float* Whh_a   = (const float*)d_in[4];
    const float* b_a     = (const float*)d_in[5];
    const float* Wih_r   = (const float*)d_in[6];
    const float* Whh_r   = (const float*)d_in[7];
    const float* b_r     = (const float*)d_in[8];
    const float* Wih_t   = (const float*)d_in[9];
    const float* Whh_t   = (const float*)d_in[10];
    const float* b_t     = (const float*)d_in[11];
    const float* e2act_w = (const float*)d_in[12];
    const float* e2act_b = (const float*)d_in[13];
    const float* e2res_w = (const float*)d_in[14];
    const float* e2res_b = (const float*)d_in[15];
    const float* e2ts_w1 = (const float*)d_in[16];
    const float* e2ts_b1 = (const float*)d_in[17];
    const float* e2ts_w2 = (const float*)d_in[18];
    const float* e2ts_b2 = (const float*)d_in[19];

    float* out_acts = (float*)d_out;                     // [1024][64][64]
    float* out_ts   = out_acts + (size_t)1024 * 64 * 64; // [1024][64]
    float* out_res  = out_ts + 1024 * 64;                // [1024][64][128]

    float* ws = (float*)d_ws;
    size_t off = 0;
    auto alloc = [&](size_t n) { float* p = ws + off; off += n; return p; };
    float* t_rec  = alloc((size_t)1024 * 512);
    float* base_a = alloc((size_t)1024 * 4096);
    float* base_r = alloc((size_t)1024 * 4096);
    float* base_t = alloc((size_t)1024 * 4096);
    float* Ea     = alloc((size_t)64 * 4096);
    float* Er_a   = alloc((size_t)64 * 4096);
    float* Er_r   = alloc((size_t)128 * 4096);
    float* Et_a   = alloc((size_t)64 * 4096);
    float* wtts   = alloc(4096);
    float* hc     = alloc((size_t)6 * 1024 * 1024);
    float* ha = hc, * ca = hc + 1048576, * hr = hc + 2097152;
    float* cr = hc + 3145728, * ht = hc + 4194304, * ct = hc + 5242880;
    float* gates_a = alloc((size_t)1024 * 4096);
    float* gates_r = alloc((size_t)1024 * 4096);
    float* gates_t = alloc((size_t)1024 * 4096);
    float* u      = alloc((size_t)1024 * 512);
    float* tsv    = alloc(1024);
    int*   aidx   = (int*)alloc(1024);
    int*   ridx   = (int*)alloc(1024);
    float* actT4  = alloc((size_t)64 * 1024);    // packed transpose of e2act_w
    float* resT4  = alloc((size_t)128 * 1024);   // packed transpose of e2res_w
    // split state: 6 arrays of 1M ushort = 3M floats
    unsigned short* hilo = (unsigned short*)alloc((size_t)3 * 1024 * 1024);
    const size_t U = 1048576;
    unsigned short* ha0 = hilo,         * ha1 = hilo + U;
    unsigned short* hr0 = hilo + 2 * U, * hr1 = hilo + 3 * U;
    unsigned short* ht0 = hilo + 4 * U, * ht1 = hilo + 5 * U;
    // split weights
    unsigned short* WA0 = (unsigned short*)alloc((size_t)2 * 1024 * 1024);
    unsigned short* WA1 = (unsigned short*)alloc((size_t)2 * 1024 * 1024);
    unsigned short* WR0 = (unsigned short*)alloc((size_t)2 * 1024 * 1024);
    unsigned short* WR1 = (unsigned short*)alloc((size_t)2 * 1024 * 1024);
    unsigned short* WT0 = (unsigned short*)alloc((size_t)2 * 1024 * 1024);
    unsigned short* WT1 = (unsigned short*)alloc((size_t)2 * 1024 * 1024);
    unsigned short* W10 = (unsigned short*)alloc((size_t)256 * 1024);
    unsigned short* W11 = (unsigned short*)alloc((size_t)256 * 1024);

    dim3 blk(256);
    init_state<<<(6 * 1024 * 1024 + 255) / 256, blk, 0, stream>>>(hc, (unsigned int*)hilo, tsv, aidx, ridx);

    // t_rec = relu(z @ z2t_w.T + z2t_b)
    gemm_f32<<<dim3(8, 8, 1), blk, 0, stream>>>(z, z2t_w, t_rec, z, z2t_w, t_rec,
                                                256, 256, 512, 256, z2t_b, 1);
    // base_* = t_rec @ Wih_*[:, :512].T + b_*
    gemm_f32<<<dim3(8, 64, 1), blk, 0, stream>>>(t_rec, Wih_a, base_a, t_rec, Wih_a, base_a,
                                                 512, 576, 4096, 512, b_a, 0);
    gemm_f32<<<dim3(8, 64, 1), blk, 0, stream>>>(t_rec, Wih_r, base_r, t_rec, Wih_r, base_r,
                                                 512, 704, 4096, 512, b_r, 0);
    gemm_f32<<<dim3(8, 64, 1), blk, 0, stream>>>(t_rec, Wih_t, base_t, t_rec, Wih_t, base_t,
                                                 512, 577, 4096, 512, b_t, 0);
    // one-hot column tables
    extract_cols<<<(64 * 4096 + 255) / 256, blk, 0, stream>>>(Wih_a, 576, 512, 64, Ea);
    extract_cols<<<(64 * 4096 + 255) / 256, blk, 0, stream>>>(Wih_r, 704, 512, 64, Er_a);
    extract_cols<<<(128 * 4096 + 255) / 256, blk, 0, stream>>>(Wih_r, 704, 576, 128, Er_r);
    extract_cols<<<(64 * 4096 + 255) / 256, blk, 0, stream>>>(Wih_t, 577, 512, 64, Et_a);
    extract_cols<<<(4096 + 255) / 256, blk, 0, stream>>>(Wih_t, 577, 576, 1, wtts);
    // head weight transposes
    transpose_pack<<<(64 * 1024 + 255) / 256, blk, 0, stream>>>(e2act_w, 1024, 64, actT4);
    transpose_pack<<<(128 * 1024 + 255) / 256, blk, 0, stream>>>(e2res_w, 1024, 128, resT4);
    // weight splits (fp16 hi/lo, lo scaled by 2^11)
    split_mat_h<<<(4194304 + 255) / 256, blk, 0, stream>>>(Whh_a, WA0, WA1, 4194304);
    split_mat_h<<<(4194304 + 255) / 256, blk, 0, stream>>>(Whh_r, WR0, WR1, 4194304);
    split_mat_h<<<(4194304 + 255) / 256, blk, 0, stream>>>(Whh_t, WT0, WT1, 4194304);
    split_mat_h<<<(524288 + 255) / 256, blk, 0, stream>>>(e2ts_w1, W10, W11, 524288);

    SPH pa = {ha0, ha1, WA0, WA1, gates_a};
    SPH pr = {hr0, hr1, WR0, WR1, gates_r};
    SPH pt = {ht0, ht1, WT0, WT1, gates_t};
    SPH pu = {ht0, ht1, W10, W11, u};

    for (int t = 0; t < 64; t++) {
        // all 3 recurrent gate GEMMs in one launch (768 blocks = 3/CU):
        // a,r,t gates depend only on PREVIOUS-step ha/hr/ht.
        gemm_f16s<<<dim3(8, 32, 3), blk, 0, stream>>>(pa, pr, pt, 1024, 4096, nullptr, 0);
        // cell a pointwise + fused act head
        lstm_pw_a<<<4096, blk, 0, stream>>>(gates_a, base_a, Ea, aidx, ha, ca, ha0, ha1);
        act_head<<<256, blk, 0, stream>>>(ha, actT4, e2act_b, out_acts, t, aidx);
        // cells r & t pointwise (uses new aidx, prev ridx/tsv)
        lstm_pw_rt<<<8192, blk, 0, stream>>>(gates_r, base_r, Er_a, Er_r, aidx, ridx,
                                             hr, cr, hr0, hr1,
                                             gates_t, base_t, Et_a, wtts, tsv,
                                             ht, ct, ht0, ht1);
        res_head<<<256, blk, 0, stream>>>(hr, resT4, e2res_b, out_res, t, ridx);
        // ts head: u = relu(ht @ e2ts_w1.T + b1)
        gemm_f16s<<<dim3(8, 4, 1), blk, 0, stream>>>(pu, pu, pu, 1024, 512, e2ts_b1, 1);
        ts_final<<<256, blk, 0, stream>>>(u, e2ts_w2, e2ts_b2, out_ts, t, tsv);
    }
}

// Round 6
// 18884.637 us; speedup vs baseline: 1.1117x; 1.1117x over previous
//
#include <hip/hip_runtime.h>
#include <math.h>

// Decoder: B=1024, Z=256, TDIM=512, CF=1024, A=64, R=128, T=64
// R6: (1) XCD-aware swizzle in the batched gate GEMM: the 8 m-blocks sharing a
//     weight slice map to ONE XCD (xcd = L%8 heuristic) -> kill ~8x W over-fetch;
//     (2) BK=64 (half the barrier rounds, same K accumulation order = bit-identical);
//     (3) 4 launches/step: BIG GEMM also computes u(t-1) (depends only on ht(t-1));
//     pw_a+act_head fused; pw_rt+res_head fused (h staged in LDS, no float h round-trip).
//     fp16 2-way-split MFMA numerics exactly as R4/R5 (verified passing).

__device__ __forceinline__ float sigf(float x) { return 1.0f / (1.0f + expf(-x)); }

typedef __attribute__((ext_vector_type(8))) _Float16 f16x8;
typedef __attribute__((ext_vector_type(4))) float f32x4;

__device__ __forceinline__ void split_f16(float x, unsigned short& hi, unsigned short& lo) {
    _Float16 h = (_Float16)x;                   // RNE f32->f16
    float r = (x - (float)h) * 2048.0f;         // exact
    _Float16 l = (_Float16)r;
    hi = __builtin_bit_cast(unsigned short, h);
    lo = __builtin_bit_cast(unsigned short, l);
}

// ---------------- fp16-split MFMA GEMM, 4-way batched + swizzled ----------------
// 128x128 tile, BK=64, 256 threads = 4 waves (2x2), each wave 64x64 (4x4 frags of 16x16).
// L in [0,768): gates GEMMs z=0..2 (M=1024,N=4096), XCD-grouped by weight slice.
// L in [768,800): u-head GEMM z=3 (M=1024,N=512).
struct SPH {
    const unsigned short* Ah; const unsigned short* Al;
    const unsigned short* Wh; const unsigned short* Wl;
    float* C; const float* bias; int N; int relu;
};

__global__ __launch_bounds__(256) void gemm4(
    SPH p0, SPH p1, SPH p2, SPH p3, int K, int Loff)
{
    int L = blockIdx.x + Loff;
    int x, y, z;
    if (L < 768) {
        int xcd = L & 7, idx = L >> 3;          // idx in [0,96)
        int group = xcd * 12 + (idx >> 3);       // 96 (y,z) groups, 12 per XCD
        x = idx & 7;
        z = group >> 5;
        y = group & 31;
    } else {
        int t2 = L - 768;                        // [0,32): u tiles
        x = t2 & 7; y = t2 >> 3; z = 3;
    }
    SPH P = z == 0 ? p0 : (z == 1 ? p1 : (z == 2 ? p2 : p3));

    __shared__ unsigned short lds[32768];   // 64KB: Ah[0:8192) Al[8192) Wh[16384) Wl[24576)
    const int tid = threadIdx.x;
    const int wave = tid >> 6, lane = tid & 63;
    const int wm = wave >> 1, wn = wave & 1;
    const int lrow = lane & 15, lq = lane >> 4;
    const int m0 = x * 128, n0 = y * 128;

    f32x4 acch[4][4], accl[4][4];
#pragma unroll
    for (int i = 0; i < 4; i++)
#pragma unroll
        for (int j = 0; j < 4; j++) {
            acch[i][j] = (f32x4){0.f, 0.f, 0.f, 0.f};
            accl[i][j] = (f32x4){0.f, 0.f, 0.f, 0.f};
        }

    for (int k0 = 0; k0 < K; k0 += 64) {
        __syncthreads();
#pragma unroll
        for (int ss = 0; ss < 2; ss++) {
            int s = wave * 2 + ss;
            int mrow = m0 + s * 16 + lrow;
            int nrow = n0 + s * 16 + lrow;
#pragma unroll
            for (int kh = 0; kh < 2; kh++) {
                int k = k0 + kh * 32 + lq * 8;
                int lo = s * 1024 + kh * 512;
                __builtin_amdgcn_global_load_lds(
                    (const __attribute__((address_space(1))) void*)(P.Ah + (size_t)mrow * K + k),
                    (__attribute__((address_space(3))) void*)&lds[lo], 16, 0, 0);
                __builtin_amdgcn_global_load_lds(
                    (const __attribute__((address_space(1))) void*)(P.Al + (size_t)mrow * K + k),
                    (__attribute__((address_space(3))) void*)&lds[8192 + lo], 16, 0, 0);
                __builtin_amdgcn_global_load_lds(
                    (const __attribute__((address_space(1))) void*)(P.Wh + (size_t)nrow * K + k),
                    (__attribute__((address_space(3))) void*)&lds[16384 + lo], 16, 0, 0);
                __builtin_amdgcn_global_load_lds(
                    (const __attribute__((address_space(1))) void*)(P.Wl + (size_t)nrow * K + k),
                    (__attribute__((address_space(3))) void*)&lds[24576 + lo], 16, 0, 0);
            }
        }
        __syncthreads();

#pragma unroll
        for (int kh = 0; kh < 2; kh++) {
            f16x8 ah[4], al[4], bh[4], bl[4];
#pragma unroll
            for (int mi = 0; mi < 4; mi++) {
                ah[mi] = *(const f16x8*)&lds[(wm * 4 + mi) * 1024 + kh * 512 + lane * 8];
                al[mi] = *(const f16x8*)&lds[8192 + (wm * 4 + mi) * 1024 + kh * 512 + lane * 8];
            }
#pragma unroll
            for (int ni = 0; ni < 4; ni++) {
                bh[ni] = *(const f16x8*)&lds[16384 + (wn * 4 + ni) * 1024 + kh * 512 + lane * 8];
                bl[ni] = *(const f16x8*)&lds[24576 + (wn * 4 + ni) * 1024 + kh * 512 + lane * 8];
            }
#pragma unroll
            for (int mi = 0; mi < 4; mi++)
#pragma unroll
                for (int ni = 0; ni < 4; ni++) {
                    acch[mi][ni] = __builtin_amdgcn_mfma_f32_16x16x32_f16(ah[mi], bh[ni], acch[mi][ni], 0, 0, 0);
                    accl[mi][ni] = __builtin_amdgcn_mfma_f32_16x16x32_f16(al[mi], bh[ni], accl[mi][ni], 0, 0, 0);
                    accl[mi][ni] = __builtin_amdgcn_mfma_f32_16x16x32_f16(ah[mi], bl[ni], accl[mi][ni], 0, 0, 0);
                }
        }
    }

    const float s_lo = 1.0f / 2048.0f;
#pragma unroll
    for (int mi = 0; mi < 4; mi++)
#pragma unroll
        for (int ni = 0; ni < 4; ni++) {
            int row = m0 + wm * 64 + mi * 16 + lq * 4;
            int col = n0 + wn * 64 + ni * 16 + lrow;
            float bv = P.bias ? P.bias[col] : 0.0f;
#pragma unroll
            for (int r = 0; r < 4; r++) {
                float v = acch[mi][ni][r] + accl[mi][ni][r] * s_lo + bv;
                if (P.relu) v = fmaxf(v, 0.0f);
                P.C[(size_t)(row + r) * P.N + col] = v;
            }
        }
}

// ---------------- fp32 GEMM (setup only) ----------------
__global__ __launch_bounds__(256) void gemm_f32(
    const float* __restrict__ A0, const float* __restrict__ W0, float* __restrict__ C0,
    const float* __restrict__ A1, const float* __restrict__ W1, float* __restrict__ C1,
    int lda, int ldw, int ldc, int K, const float* __restrict__ bias, int relu)
{
    const float* Ap = blockIdx.z ? A1 : A0;
    const float* Wp = blockIdx.z ? W1 : W0;
    float*       Cp = blockIdx.z ? C1 : C0;
    __shared__ float As[16][128];
    __shared__ float Bs[16][64];
    const int tid = threadIdx.x;
    const int m0 = blockIdx.x * 128, n0 = blockIdx.y * 64;
    const int tx = tid & 7, ty = tid >> 3;
    const bool wal = (ldw & 3) == 0;
    float acc[4][8];
#pragma unroll
    for (int i = 0; i < 4; i++)
#pragma unroll
        for (int j = 0; j < 8; j++) acc[i][j] = 0.0f;

    for (int k0 = 0; k0 < K; k0 += 16) {
        __syncthreads();
#pragma unroll
        for (int q = 0; q < 2; q++) {
            int t2 = tid + q * 256;
            int kq = t2 & 3, m = t2 >> 2;
            float4 v = *(const float4*)(Ap + (size_t)(m0 + m) * lda + k0 + kq * 4);
            As[kq * 4 + 0][m] = v.x; As[kq * 4 + 1][m] = v.y;
            As[kq * 4 + 2][m] = v.z; As[kq * 4 + 3][m] = v.w;
        }
        {
            int kq = tid & 3, n = tid >> 2;
            const float* src = Wp + (size_t)(n0 + n) * ldw + k0 + kq * 4;
            float4 v;
            if (wal) v = *(const float4*)src;
            else { v.x = src[0]; v.y = src[1]; v.z = src[2]; v.w = src[3]; }
            Bs[kq * 4 + 0][n] = v.x; Bs[kq * 4 + 1][n] = v.y;
            Bs[kq * 4 + 2][n] = v.z; Bs[kq * 4 + 3][n] = v.w;
        }
        __syncthreads();
#pragma unroll
        for (int k = 0; k < 16; k++) {
            float a4[4], b8[8];
            *(float4*)a4 = *(const float4*)&As[k][ty * 4];
            *(float4*)(b8) = *(const float4*)&Bs[k][tx * 8];
            *(float4*)(b8 + 4) = *(const float4*)&Bs[k][tx * 8 + 4];
#pragma unroll
            for (int i = 0; i < 4; i++)
#pragma unroll
                for (int j = 0; j < 8; j++) acc[i][j] = fmaf(a4[i], b8[j], acc[i][j]);
        }
    }
#pragma unroll
    for (int i = 0; i < 4; i++) {
        int m = m0 + ty * 4 + i;
        float vb[8];
#pragma unroll
        for (int j = 0; j < 8; j++) {
            float v = acc[i][j];
            if (bias) v += bias[n0 + tx * 8 + j];
            if (relu) v = fmaxf(v, 0.0f);
            vb[j] = v;
        }
        float* dst = Cp + (size_t)m * ldc + n0 + tx * 8;
        *(float4*)dst = make_float4(vb[0], vb[1], vb[2], vb[3]);
        *(float4*)(dst + 4) = make_float4(vb[4], vb[5], vb[6], vb[7]);
    }
}

// ------------- fused cell a: pointwise LSTM + act head (softmax+argmax) -------------
// 256 blocks x 512 thr; block handles batch rows 4b..4b+3. h staged in LDS.
__global__ __launch_bounds__(512) void fused_a(
    const float* __restrict__ gates, const float* __restrict__ base,
    const float* __restrict__ Ea, int* __restrict__ aidx,
    float* __restrict__ c, unsigned short* __restrict__ h_hi, unsigned short* __restrict__ h_lo,
    const float* __restrict__ wT4, const float* __restrict__ bias,
    float* __restrict__ out_probs, int t)
{
    __shared__ float Hs[4][1024];
    const int tid = threadIdx.x;
    const int b0 = blockIdx.x * 4;
#pragma unroll
    for (int q = 0; q < 8; q++) {
        int e = tid + q * 512;              // [0,4096)
        int row = e >> 10, j = e & 1023;
        int b = b0 + row;
        size_t r = (size_t)b * 4096 + j;
        size_t i = (size_t)b * 1024 + j;
        const float* e1 = Ea + (size_t)aidx[b] * 4096 + j;
        float gi = gates[r]        + base[r]        + e1[0];
        float gf = gates[r + 1024] + base[r + 1024] + e1[1024];
        float gg = gates[r + 2048] + base[r + 2048] + e1[2048];
        float go = gates[r + 3072] + base[r + 3072] + e1[3072];
        float cn = sigf(gf) * c[i] + sigf(gi) * tanhf(gg);
        c[i] = cn;
        float hn = sigf(go) * tanhf(cn);
        Hs[row][j] = hn;
        split_f16(hn, h_hi[i], h_lo[i]);
    }
    __syncthreads();
    const int wave = tid >> 6, lane = tid & 63;
    if (wave < 4) {
        int b = b0 + wave;
        float acc = bias[lane];
        const float4* arow = (const float4*)Hs[wave];
#pragma unroll 4
        for (int k4 = 0; k4 < 256; k4++) {
            float4 a4 = arow[k4];
            float4 w4 = *(const float4*)(wT4 + ((size_t)k4 * 64 + lane) * 4);
            acc += a4.x * w4.x + a4.y * w4.y + a4.z * w4.z + a4.w * w4.w;
        }
        float v = acc; int idx = lane;
#pragma unroll
        for (int off = 32; off; off >>= 1) {
            float ov = __shfl_xor(v, off);
            int   oi = __shfl_xor(idx, off);
            if (ov > v || (ov == v && oi < idx)) { v = ov; idx = oi; }
        }
        float e = expf(acc - v);
        float s = e;
#pragma unroll
        for (int off = 32; off; off >>= 1) s += __shfl_xor(s, off);
        out_probs[((size_t)b * 64 + t) * 64 + lane] = e / s;
        if (lane == 0) aidx[b] = idx;
    }
}

// ------------- fused cells r+t: pointwise LSTM x2 + res head -------------
__global__ __launch_bounds__(512) void fused_rt(
    const float* __restrict__ gates_r, const float* __restrict__ base_r,
    const float* __restrict__ Er_a, const float* __restrict__ Er_r,
    const int* __restrict__ aidx, int* __restrict__ ridx,
    float* __restrict__ cr, unsigned short* __restrict__ hr0, unsigned short* __restrict__ hr1,
    const float* __restrict__ gates_t, const float* __restrict__ base_t,
    const float* __restrict__ Et_a, const float* __restrict__ wtts, const float* __restrict__ tsv,
    float* __restrict__ ct, unsigned short* __restrict__ ht0, unsigned short* __restrict__ ht1,
    const float* __restrict__ wT4, const float* __restrict__ bias,
    float* __restrict__ out_probs, int t)
{
    __shared__ float Hs[4][1024];
    const int tid = threadIdx.x;
    const int b0 = blockIdx.x * 4;
#pragma unroll
    for (int q = 0; q < 16; q++) {
        int e = tid + q * 512;              // [0,8192): q<8 -> cell r, q>=8 -> cell t
        int e2 = e & 4095;
        int row = e2 >> 10, j = e2 & 1023;
        int b = b0 + row;
        size_t r = (size_t)b * 4096 + j;
        size_t i = (size_t)b * 1024 + j;
        if (e < 4096) {
            const float* e1 = Er_a + (size_t)aidx[b] * 4096 + j;
            const float* eh = Er_r + (size_t)ridx[b] * 4096 + j;
            float gi = gates_r[r]        + base_r[r]        + e1[0]    + eh[0];
            float gf = gates_r[r + 1024] + base_r[r + 1024] + e1[1024] + eh[1024];
            float gg = gates_r[r + 2048] + base_r[r + 2048] + e1[2048] + eh[2048];
            float go = gates_r[r + 3072] + base_r[r + 3072] + e1[3072] + eh[3072];
            float cn = sigf(gf) * cr[i] + sigf(gi) * tanhf(gg);
            cr[i] = cn;
            float hn = sigf(go) * tanhf(cn);
            Hs[row][j] = hn;
            split_f16(hn, hr0[i], hr1[i]);
        } else {
            const float* e1 = Et_a + (size_t)aidx[b] * 4096 + j;
            float tv = tsv[b];
            float gi = gates_t[r]        + base_t[r]        + e1[0];
            float gf = gates_t[r + 1024] + base_t[r + 1024] + e1[1024];
            float gg = gates_t[r + 2048] + base_t[r + 2048] + e1[2048];
            float go = gates_t[r + 3072] + base_t[r + 3072] + e1[3072];
            gi = fmaf(tv, wtts[j], gi);        gf = fmaf(tv, wtts[j + 1024], gf);
            gg = fmaf(tv, wtts[j + 2048], gg); go = fmaf(tv, wtts[j + 3072], go);
            float cn = sigf(gf) * ct[i] + sigf(gi) * tanhf(gg);
            ct[i] = cn;
            float hn = sigf(go) * tanhf(cn);
            split_f16(hn, ht0[i], ht1[i]);
        }
    }
    __syncthreads();
    const int wave = tid >> 6, lane = tid & 63;
    if (wave < 4) {
        int b = b0 + wave;
        float acc0 = bias[lane], acc1 = bias[lane + 64];
        const float4* arow = (const float4*)Hs[wave];
#pragma unroll 4
        for (int k4 = 0; k4 < 256; k4++) {
            float4 a4 = arow[k4];
            float4 w40 = *(const float4*)(wT4 + ((size_t)k4 * 128 + lane) * 4);
            float4 w41 = *(const float4*)(wT4 + ((size_t)k4 * 128 + lane + 64) * 4);
            acc0 += a4.x * w40.x + a4.y * w40.y + a4.z * w40.z + a4.w * w40.w;
            acc1 += a4.x * w41.x + a4.y * w41.y + a4.z * w41.z + a4.w * w41.w;
        }
        float v = acc0; int idx = lane;
        if (acc1 > v) { v = acc1; idx = lane + 64; }
#pragma unroll
        for (int off = 32; off; off >>= 1) {
            float ov = __shfl_xor(v, off);
            int   oi = __shfl_xor(idx, off);
            if (ov > v || (ov == v && oi < idx)) { v = ov; idx = oi; }
        }
        float e0 = expf(acc0 - v), e1 = expf(acc1 - v);
        float s = e0 + e1;
#pragma unroll
        for (int off = 32; off; off >>= 1) s += __shfl_xor(s, off);
        float* dst = out_probs + ((size_t)b * 64 + t) * 128;
        dst[lane] = e0 / s; dst[lane + 64] = e1 / s;
        if (lane == 0) ridx[b] = idx;
    }
}

// ------------- ts final -------------
__global__ __launch_bounds__(256) void ts_final(
    const float* __restrict__ u, const float* __restrict__ w2, const float* __restrict__ b2,
    float* __restrict__ out_ts, int t, float* __restrict__ tsv)
{
    int lane = threadIdx.x & 63;
    int b = blockIdx.x * 4 + (threadIdx.x >> 6);
    const float* ur = u + (size_t)b * 512;
    float s = 0.0f;
#pragma unroll
    for (int q = 0; q < 8; q++) s = fmaf(ur[lane + q * 64], w2[lane + q * 64], s);
#pragma unroll
    for (int off = 32; off; off >>= 1) s += __shfl_xor(s, off);
    if (lane == 0) {
        float r = s + b2[0];
        out_ts[b * 64 + t] = r;
        tsv[b] = r;
    }
}

// ------------- setup kernels -------------
__global__ void extract_cols(const float* __restrict__ Wih, int ldw, int col0, int ncols,
                             float* __restrict__ E)
{
    int i = blockIdx.x * 256 + threadIdx.x;
    if (i >= ncols * 4096) return;
    int c = i % ncols, j = i / ncols;
    E[(size_t)c * 4096 + j] = Wih[(size_t)j * ldw + col0 + c];
}

__global__ void split_mat_h(const float* __restrict__ X,
                            unsigned short* __restrict__ hi, unsigned short* __restrict__ lo, int n)
{
    int i = blockIdx.x * 256 + threadIdx.x;
    if (i >= n) return;
    split_f16(X[i], hi[i], lo[i]);
}

// pack-transpose: out[((k>>2)*C + c)*4 + (k&3)] = W[c*K + k]
__global__ void transpose_pack(const float* __restrict__ W, int K, int C, float* __restrict__ out)
{
    int i = blockIdx.x * 256 + threadIdx.x;
    if (i >= C * K) return;
    int c = i / K, k = i - c * K;
    out[(((size_t)(k >> 2) * C + c) << 2) + (k & 3)] = W[i];
}

__global__ void init_state(float* __restrict__ hc, unsigned int* __restrict__ hilo,
                           float* __restrict__ tsv, int* __restrict__ aidx, int* __restrict__ ridx)
{
    int i = blockIdx.x * 256 + threadIdx.x;
    if (i < 6 * 1024 * 1024) hc[i] = 0.0f;
    if (i < 3 * 1024 * 1024) hilo[i] = 0u;          // 6M ushort of split state
    if (i < 1024) { tsv[i] = 0.0f; aidx[i] = 63; ridx[i] = 127; }
}

extern "C" void kernel_launch(void* const* d_in, const int* in_sizes, int n_in,
                              void* d_out, int out_size, void* d_ws, size_t ws_size,
                              hipStream_t stream)
{
    const float* z       = (const float*)d_in[0];
    const float* z2t_w   = (const float*)d_in[1];
    const float* z2t_b   = (const float*)d_in[2];
    const float* Wih_a   = (const float*)d_in[3];
    const float* Whh_a   = (const float*)d_in[4];
    const float* b_a     = (const float*)d_in[5];
    const float* Wih_r   = (const float*)d_in[6];
    const float* Whh_r   = (const float*)d_in[7];
    const float* b_r     = (const float*)d_in[8];
    const float* Wih_t   = (const float*)d_in[9];
    const float* Whh_t   = (const float*)d_in[10];
    const float* b_t     = (const float*)d_in[11];
    const float* e2act_w = (const float*)d_in[12];
    const float* e2act_b = (const float*)d_in[13];
    const float* e2res_w = (const float*)d_in[14];
    const float* e2res_b = (const float*)d_in[15];
    const float* e2ts_w1 = (const float*)d_in[16];
    const float* e2ts_b1 = (const float*)d_in[17];
    const float* e2ts_w2 = (const float*)d_in[18];
    const float* e2ts_b2 = (const float*)d_in[19];

    float* out_acts = (float*)d_out;                     // [1024][64][64]
    float* out_ts   = out_acts + (size_t)1024 * 64 * 64; // [1024][64]
    float* out_res  = out_ts + 1024 * 64;                // [1024][64][128]

    float* ws = (float*)d_ws;
    size_t off = 0;
    auto alloc = [&](size_t n) { float* p = ws + off; off += n; return p; };
    float* t_rec  = alloc((size_t)1024 * 512);
    float* base_a = alloc((size_t)1024 * 4096);
    float* base_r = alloc((size_t)1024 * 4096);
    float* base_t = alloc((size_t)1024 * 4096);
    float* Ea     = alloc((size_t)64 * 4096);
    float* Er_a   = alloc((size_t)64 * 4096);
    float* Er_r   = alloc((size_t)128 * 4096);
    float* Et_a   = alloc((size_t)64 * 4096);
    float* wtts   = alloc(4096);
    float* hc     = alloc((size_t)6 * 1024 * 1024);
    float* ca = hc + 1048576;
    float* cr = hc + 3145728;
    float* ct = hc + 5242880;
    float* gates_a = alloc((size_t)1024 * 4096);
    float* gates_r = alloc((size_t)1024 * 4096);
    float* gates_t = alloc((size_t)1024 * 4096);
    float* u      = alloc((size_t)1024 * 512);
    float* tsv    = alloc(1024);
    int*   aidx   = (int*)alloc(1024);
    int*   ridx   = (int*)alloc(1024);
    float* actT4  = alloc((size_t)64 * 1024);    // packed transpose of e2act_w
    float* resT4  = alloc((size_t)128 * 1024);   // packed transpose of e2res_w
    // split state: 6 arrays of 1M ushort = 3M floats
    unsigned short* hilo = (unsigned short*)alloc((size_t)3 * 1024 * 1024);
    const size_t U = 1048576;
    unsigned short* ha0 = hilo,         * ha1 = hilo + U;
    unsigned short* hr0 = hilo + 2 * U, * hr1 = hilo + 3 * U;
    unsigned short* ht0 = hilo + 4 * U, * ht1 = hilo + 5 * U;
    // split weights
    unsigned short* WA0 = (unsigned short*)alloc((size_t)2 * 1024 * 1024);
    unsigned short* WA1 = (unsigned short*)alloc((size_t)2 * 1024 * 1024);
    unsigned short* WR0 = (unsigned short*)alloc((size_t)2 * 1024 * 1024);
    unsigned short* WR1 = (unsigned short*)alloc((size_t)2 * 1024 * 1024);
    unsigned short* WT0 = (unsigned short*)alloc((size_t)2 * 1024 * 1024);
    unsigned short* WT1 = (unsigned short*)alloc((size_t)2 * 1024 * 1024);
    unsigned short* W10 = (unsigned short*)alloc((size_t)256 * 1024);
    unsigned short* W11 = (unsigned short*)alloc((size_t)256 * 1024);

    dim3 blk(256);
    init_state<<<(6 * 1024 * 1024 + 255) / 256, blk, 0, stream>>>(hc, (unsigned int*)hilo, tsv, aidx, ridx);

    // t_rec = relu(z @ z2t_w.T + z2t_b)
    gemm_f32<<<dim3(8, 8, 1), blk, 0, stream>>>(z, z2t_w, t_rec, z, z2t_w, t_rec,
                                                256, 256, 512, 256, z2t_b, 1);
    // base_* = t_rec @ Wih_*[:, :512].T + b_*
    gemm_f32<<<dim3(8, 64, 1), blk, 0, stream>>>(t_rec, Wih_a, base_a, t_rec, Wih_a, base_a,
                                                 512, 576, 4096, 512, b_a, 0);
    gemm_f32<<<dim3(8, 64, 1), blk, 0, stream>>>(t_rec, Wih_r, base_r, t_rec, Wih_r, base_r,
                                                 512, 704, 4096, 512, b_r, 0);
    gemm_f32<<<dim3(8, 64, 1), blk, 0, stream>>>(t_rec, Wih_t, base_t, t_rec, Wih_t, base_t,
                                                 512, 577, 4096, 512, b_t, 0);
    // one-hot column tables
    extract_cols<<<(64 * 4096 + 255) / 256, blk, 0, stream>>>(Wih_a, 576, 512, 64, Ea);
    extract_cols<<<(64 * 4096 + 255) / 256, blk, 0, stream>>>(Wih_r, 704, 512, 64, Er_a);
    extract_cols<<<(128 * 4096 + 255) / 256, blk, 0, stream>>>(Wih_r, 704, 576, 128, Er_r);
    extract_cols<<<(64 * 4096 + 255) / 256, blk, 0, stream>>>(Wih_t, 577, 512, 64, Et_a);
    extract_cols<<<(4096 + 255) / 256, blk, 0, stream>>>(Wih_t, 577, 576, 1, wtts);
    // head weight transposes
    transpose_pack<<<(64 * 1024 + 255) / 256, blk, 0, stream>>>(e2act_w, 1024, 64, actT4);
    transpose_pack<<<(128 * 1024 + 255) / 256, blk, 0, stream>>>(e2res_w, 1024, 128, resT4);
    // weight splits (fp16 hi/lo, lo scaled by 2^11)
    split_mat_h<<<(4194304 + 255) / 256, blk, 0, stream>>>(Whh_a, WA0, WA1, 4194304);
    split_mat_h<<<(4194304 + 255) / 256, blk, 0, stream>>>(Whh_r, WR0, WR1, 4194304);
    split_mat_h<<<(4194304 + 255) / 256, blk, 0, stream>>>(Whh_t, WT0, WT1, 4194304);
    split_mat_h<<<(524288 + 255) / 256, blk, 0, stream>>>(e2ts_w1, W10, W11, 524288);

    SPH pa = {ha0, ha1, WA0, WA1, gates_a, nullptr, 4096, 0};
    SPH pr = {hr0, hr1, WR0, WR1, gates_r, nullptr, 4096, 0};
    SPH pt = {ht0, ht1, WT0, WT1, gates_t, nullptr, 4096, 0};
    SPH pu = {ht0, ht1, W10, W11, u, e2ts_b1, 512, 1};

    for (int t = 0; t < 64; t++) {
        // BIG: gates_a/r/t(t) from h*(t-1), plus u(t-1) from ht(t-1). Swizzled, 800 blocks.
        gemm4<<<800, blk, 0, stream>>>(pa, pr, pt, pu, 1024, 0);
        // ts(t-1) from u(t-1); tsv(t-1) consumed by fused_rt below.
        if (t > 0)
            ts_final<<<256, blk, 0, stream>>>(u, e2ts_w2, e2ts_b2, out_ts, t - 1, tsv);
        // cell a pointwise + act head
        fused_a<<<256, dim3(512), 0, stream>>>(gates_a, base_a, Ea, aidx, ca, ha0, ha1,
                                               actT4, e2act_b, out_acts, t);
        // cells r,t pointwise + res head
        fused_rt<<<256, dim3(512), 0, stream>>>(gates_r, base_r, Er_a, Er_r, aidx, ridx,
                                                cr, hr0, hr1,
                                                gates_t, base_t, Et_a, wtts, tsv,
                                                ct, ht0, ht1,
                                                resT4, e2res_b, out_res, t);
    }
    // epilogue: u(63) + ts(63)
    gemm4<<<32, blk, 0, stream>>>(pa, pr, pt, pu, 1024, 768);
    ts_final<<<256, blk, 0, stream>>>(u, e2ts_w2, e2ts_b2, out_ts, 63, tsv);
}

// Round 7
// 16521.567 us; speedup vs baseline: 1.2707x; 1.1430x over previous
//
#include <hip/hip_runtime.h>
#include <math.h>

// Decoder: B=1024, Z=256, TDIM=512, CF=1024, A=64, R=128, T=64
// R7: LSTM pointwise fused INTO the GEMM epilogue via gate-grouped N-tiling
//     (block N-tile = 4 gates x same j-range; fragment ni == gate -> thread-local LSTM).
//     3 launches/step: step1[a-GEMM+LSTM | u-GEMM | res_head(t-1)] -> heads[act+ts(t-1)]
//     -> step3[r&t GEMM+LSTM]. h-split buffers ping-pong (read t-1, write t, same launch).
//     fp16 2-way-split MFMA numerics bit-identical to R4-R6 (verified passing).

__device__ __forceinline__ float sigf(float x) { return 1.0f / (1.0f + expf(-x)); }

typedef __attribute__((ext_vector_type(8))) _Float16 f16x8;
typedef __attribute__((ext_vector_type(4))) float f32x4;

__device__ __forceinline__ void split_f16(float x, unsigned short& hi, unsigned short& lo) {
    _Float16 h = (_Float16)x;                   // RNE f32->f16
    float r = (x - (float)h) * 2048.0f;         // exact
    _Float16 l = (_Float16)r;
    hi = __builtin_bit_cast(unsigned short, h);
    lo = __builtin_bit_cast(unsigned short, l);
}

#define GLDS(gp, lp) __builtin_amdgcn_global_load_lds( \
    (const __attribute__((address_space(1))) void*)(gp), \
    (__attribute__((address_space(3))) void*)(lp), 16, 0, 0)

// ---------------- step1: a-cell GEMM+LSTM | u GEMM | res head ----------------
// a: 128x64 tiles (64 N = 4 gates x 16 j), 4 waves (wm=wave, 32 rows each), ni=gate.
// u: 128x64 tiles over N=512.
// L<512: a (XCD-swizzled); 512..575: u; 576..831: res head for step t-1.
__global__ __launch_bounds__(256) void step1(
    const unsigned short* __restrict__ Ah, const unsigned short* __restrict__ Al,
    const unsigned short* __restrict__ WA0, const unsigned short* __restrict__ WA1,
    const float* __restrict__ base_a, const float* __restrict__ Ea, const int* __restrict__ aidx,
    float* __restrict__ ca, unsigned short* __restrict__ oAh, unsigned short* __restrict__ oAl,
    float* __restrict__ haf,
    const unsigned short* __restrict__ Th, const unsigned short* __restrict__ Tl,
    const unsigned short* __restrict__ W10, const unsigned short* __restrict__ W11,
    const float* __restrict__ b1, float* __restrict__ u,
    const float* __restrict__ hrf, const float* __restrict__ resT4, const float* __restrict__ resb,
    float* __restrict__ out_res, int* __restrict__ ridx, int t, int Loff)
{
    int L = blockIdx.x + Loff;
    if (L >= 576) {
        // ---- res head for step t-1 ----
        if (t == 0) return;
        int lane = threadIdx.x & 63, w = threadIdx.x >> 6;
        int b = (L - 576) * 4 + w;
        float acc0 = resb[lane], acc1 = resb[lane + 64];
        const float4* arow = (const float4*)(hrf + (size_t)b * 1024);
#pragma unroll 4
        for (int k4 = 0; k4 < 256; k4++) {
            float4 a4 = arow[k4];
            float4 w40 = *(const float4*)(resT4 + ((size_t)k4 * 128 + lane) * 4);
            float4 w41 = *(const float4*)(resT4 + ((size_t)k4 * 128 + lane + 64) * 4);
            acc0 += a4.x * w40.x + a4.y * w40.y + a4.z * w40.z + a4.w * w40.w;
            acc1 += a4.x * w41.x + a4.y * w41.y + a4.z * w41.z + a4.w * w41.w;
        }
        float v = acc0; int idx = lane;
        if (acc1 > v) { v = acc1; idx = lane + 64; }
#pragma unroll
        for (int off = 32; off; off >>= 1) {
            float ov = __shfl_xor(v, off);
            int   oi = __shfl_xor(idx, off);
            if (ov > v || (ov == v && oi < idx)) { v = ov; idx = oi; }
        }
        float e0 = expf(acc0 - v), e1 = expf(acc1 - v);
        float s = e0 + e1;
#pragma unroll
        for (int off = 32; off; off >>= 1) s += __shfl_xor(s, off);
        float* dst = out_res + ((size_t)b * 64 + (t - 1)) * 128;
        dst[lane] = e0 / s; dst[lane + 64] = e1 / s;
        if (lane == 0) ridx[b] = idx;
        return;
    }

    // ---- GEMM part (a or u) ----
    __shared__ unsigned short lds[24576];   // 48KB: Ah[0,8192) Al[8192,16384) Wh[16384,20480) Wl[20480,24576)
    const unsigned short *pAh, *pAl, *pWh, *pWl;
    int x, jy; bool isA;
    if (L < 512) {
        isA = true;
        int xcd = L & 7, idx = L >> 3;
        jy = xcd * 8 + (idx >> 3);       // j-tile 0..63 (j0 = jy*16)
        x = idx & 7;
        pAh = Ah; pAl = Al; pWh = WA0; pWl = WA1;
    } else {
        isA = false;
        int t2 = L - 512;
        x = t2 & 7; jy = t2 >> 3;        // u: n0 = jy*64
        pAh = Th; pAl = Tl; pWh = W10; pWl = W11;
    }
    const int tid = threadIdx.x, wave = tid >> 6, lane = tid & 63;
    const int lrow = lane & 15, lq = lane >> 4;
    const int m0 = x * 128;

    f32x4 acch[2][4], accl[2][4];
#pragma unroll
    for (int i = 0; i < 2; i++)
#pragma unroll
        for (int j = 0; j < 4; j++) {
            acch[i][j] = (f32x4){0.f, 0.f, 0.f, 0.f};
            accl[i][j] = (f32x4){0.f, 0.f, 0.f, 0.f};
        }

    for (int k0 = 0; k0 < 1024; k0 += 64) {
        __syncthreads();
#pragma unroll
        for (int ss = 0; ss < 2; ss++) {
            int s = wave * 2 + ss;
            int mrow = m0 + s * 16 + lrow;
            int nrow = isA ? (wave * 1024 + jy * 16 + lrow) : (jy * 64 + wave * 16 + lrow);
#pragma unroll
            for (int kh = 0; kh < 2; kh++) {
                int k = k0 + kh * 32 + lq * 8;
                GLDS(pAh + (size_t)mrow * 1024 + k, &lds[s * 1024 + kh * 512]);
                GLDS(pAl + (size_t)mrow * 1024 + k, &lds[8192 + s * 1024 + kh * 512]);
                if (ss == 0) {
                    GLDS(pWh + (size_t)nrow * 1024 + k, &lds[16384 + wave * 1024 + kh * 512]);
                    GLDS(pWl + (size_t)nrow * 1024 + k, &lds[20480 + wave * 1024 + kh * 512]);
                }
            }
        }
        __syncthreads();
#pragma unroll
        for (int kh = 0; kh < 2; kh++) {
            f16x8 ah[2], al[2], bh[4], bl[4];
#pragma unroll
            for (int mi = 0; mi < 2; mi++) {
                ah[mi] = *(const f16x8*)&lds[(wave * 2 + mi) * 1024 + kh * 512 + lane * 8];
                al[mi] = *(const f16x8*)&lds[8192 + (wave * 2 + mi) * 1024 + kh * 512 + lane * 8];
            }
#pragma unroll
            for (int ni = 0; ni < 4; ni++) {
                bh[ni] = *(const f16x8*)&lds[16384 + ni * 1024 + kh * 512 + lane * 8];
                bl[ni] = *(const f16x8*)&lds[20480 + ni * 1024 + kh * 512 + lane * 8];
            }
#pragma unroll
            for (int mi = 0; mi < 2; mi++)
#pragma unroll
                for (int ni = 0; ni < 4; ni++) {
                    acch[mi][ni] = __builtin_amdgcn_mfma_f32_16x16x32_f16(ah[mi], bh[ni], acch[mi][ni], 0, 0, 0);
                    accl[mi][ni] = __builtin_amdgcn_mfma_f32_16x16x32_f16(al[mi], bh[ni], accl[mi][ni], 0, 0, 0);
                    accl[mi][ni] = __builtin_amdgcn_mfma_f32_16x16x32_f16(ah[mi], bl[ni], accl[mi][ni], 0, 0, 0);
                }
        }
    }

    const float s_lo = 1.0f / 2048.0f;
    if (isA) {
        // fused LSTM-a epilogue: ni == gate, thread-local
        int j = jy * 16 + lrow;
#pragma unroll
        for (int mi = 0; mi < 2; mi++)
#pragma unroll
            for (int r = 0; r < 4; r++) {
                int row = m0 + wave * 32 + mi * 16 + lq * 4 + r;
                size_t rb = (size_t)row * 4096 + j;
                const float* e1 = Ea + (size_t)aidx[row] * 4096 + j;
                float gi = acch[mi][0][r] + accl[mi][0][r] * s_lo + base_a[rb]        + e1[0];
                float gf = acch[mi][1][r] + accl[mi][1][r] * s_lo + base_a[rb + 1024] + e1[1024];
                float gg = acch[mi][2][r] + accl[mi][2][r] * s_lo + base_a[rb + 2048] + e1[2048];
                float go = acch[mi][3][r] + accl[mi][3][r] * s_lo + base_a[rb + 3072] + e1[3072];
                size_t ci = (size_t)row * 1024 + j;
                float cn = sigf(gf) * ca[ci] + sigf(gi) * tanhf(gg);
                ca[ci] = cn;
                float hn = sigf(go) * tanhf(cn);
                haf[ci] = hn;
                split_f16(hn, oAh[ci], oAl[ci]);
            }
    } else {
        // u = relu(ht @ W1^T + b1)
#pragma unroll
        for (int mi = 0; mi < 2; mi++)
#pragma unroll
            for (int ni = 0; ni < 4; ni++) {
                int col = jy * 64 + ni * 16 + lrow;
                float bv = b1[col];
#pragma unroll
                for (int r = 0; r < 4; r++) {
                    int row = m0 + wave * 32 + mi * 16 + lq * 4 + r;
                    float v = acch[mi][ni][r] + accl[mi][ni][r] * s_lo + bv;
                    u[(size_t)row * 512 + col] = fmaxf(v, 0.0f);
                }
            }
    }
}

// ---------------- step3: r & t cell GEMM + fused LSTM epilogue ----------------
// 128x128 tiles (128 N = 4 gates x 32 j), waves 2x2 (wm rows, wn = j-half), ni=gate.
__global__ __launch_bounds__(256) void step3(
    const unsigned short* __restrict__ Rh, const unsigned short* __restrict__ Rl,
    const unsigned short* __restrict__ WR0, const unsigned short* __restrict__ WR1,
    const float* __restrict__ base_r, const float* __restrict__ Er_a, const float* __restrict__ Er_r,
    const int* __restrict__ aidx, const int* __restrict__ ridx, const float* __restrict__ tsv,
    float* __restrict__ cr, unsigned short* __restrict__ oRh, unsigned short* __restrict__ oRl,
    float* __restrict__ hrf,
    const unsigned short* __restrict__ Th, const unsigned short* __restrict__ Tl,
    const unsigned short* __restrict__ WT0, const unsigned short* __restrict__ WT1,
    const float* __restrict__ base_t, const float* __restrict__ Et_a, const float* __restrict__ wtts,
    float* __restrict__ ct, unsigned short* __restrict__ oTh, unsigned short* __restrict__ oTl)
{
    __shared__ unsigned short lds[32768];   // 64KB: Ah Al Bh Bl @ 8192 each
    int L = blockIdx.x;
    int xcd = L & 7, idx = L >> 3;
    int g = xcd * 8 + (idx >> 3);            // 64 (z,y) groups
    int x = idx & 7;
    int z = g >> 5, y = g & 31;
    const unsigned short* pAh = z ? Th : Rh;
    const unsigned short* pAl = z ? Tl : Rl;
    const unsigned short* pWh = z ? WT0 : WR0;
    const unsigned short* pWl = z ? WT1 : WR1;

    const int tid = threadIdx.x, wave = tid >> 6, lane = tid & 63;
    const int wm = wave >> 1, wn = wave & 1;
    const int lrow = lane & 15, lq = lane >> 4;
    const int m0 = x * 128, j0 = y * 32;

    f32x4 acch[4][4], accl[4][4];
#pragma unroll
    for (int i = 0; i < 4; i++)
#pragma unroll
        for (int j = 0; j < 4; j++) {
            acch[i][j] = (f32x4){0.f, 0.f, 0.f, 0.f};
            accl[i][j] = (f32x4){0.f, 0.f, 0.f, 0.f};
        }

    for (int k0 = 0; k0 < 1024; k0 += 64) {
        __syncthreads();
#pragma unroll
        for (int ss = 0; ss < 2; ss++) {
            int s = wave * 2 + ss;
            int mrow = m0 + s * 16 + lrow;
            int nrow = (s >> 1) * 1024 + j0 + (s & 1) * 16 + lrow;   // gate = s>>1
#pragma unroll
            for (int kh = 0; kh < 2; kh++) {
                int k = k0 + kh * 32 + lq * 8;
                GLDS(pAh + (size_t)mrow * 1024 + k, &lds[s * 1024 + kh * 512]);
                GLDS(pAl + (size_t)mrow * 1024 + k, &lds[8192 + s * 1024 + kh * 512]);
                GLDS(pWh + (size_t)nrow * 1024 + k, &lds[16384 + s * 1024 + kh * 512]);
                GLDS(pWl + (size_t)nrow * 1024 + k, &lds[24576 + s * 1024 + kh * 512]);
            }
        }
        __syncthreads();
#pragma unroll
        for (int kh = 0; kh < 2; kh++) {
            f16x8 ah[4], al[4], bh[4], bl[4];
#pragma unroll
            for (int mi = 0; mi < 4; mi++) {
                ah[mi] = *(const f16x8*)&lds[(wm * 4 + mi) * 1024 + kh * 512 + lane * 8];
                al[mi] = *(const f16x8*)&lds[8192 + (wm * 4 + mi) * 1024 + kh * 512 + lane * 8];
            }
#pragma unroll
            for (int ni = 0; ni < 4; ni++) {
                bh[ni] = *(const f16x8*)&lds[16384 + (ni * 2 + wn) * 1024 + kh * 512 + lane * 8];
                bl[ni] = *(const f16x8*)&lds[24576 + (ni * 2 + wn) * 1024 + kh * 512 + lane * 8];
            }
#pragma unroll
            for (int mi = 0; mi < 4; mi++)
#pragma unroll
                for (int ni = 0; ni < 4; ni++) {
                    acch[mi][ni] = __builtin_amdgcn_mfma_f32_16x16x32_f16(ah[mi], bh[ni], acch[mi][ni], 0, 0, 0);
                    accl[mi][ni] = __builtin_amdgcn_mfma_f32_16x16x32_f16(al[mi], bh[ni], accl[mi][ni], 0, 0, 0);
                    accl[mi][ni] = __builtin_amdgcn_mfma_f32_16x16x32_f16(ah[mi], bl[ni], accl[mi][ni], 0, 0, 0);
                }
        }
    }

    const float s_lo = 1.0f / 2048.0f;
    const int j = j0 + wn * 16 + lrow;
    if (z == 0) {
        // cell r
#pragma unroll
        for (int mi = 0; mi < 4; mi++)
#pragma unroll
            for (int r = 0; r < 4; r++) {
                int row = m0 + wm * 64 + mi * 16 + lq * 4 + r;
                size_t rb = (size_t)row * 4096 + j;
                const float* e1 = Er_a + (size_t)aidx[row] * 4096 + j;
                const float* e2 = Er_r + (size_t)ridx[row] * 4096 + j;
                float gi = acch[mi][0][r] + accl[mi][0][r] * s_lo + base_r[rb]        + e1[0]    + e2[0];
                float gf = acch[mi][1][r] + accl[mi][1][r] * s_lo + base_r[rb + 1024] + e1[1024] + e2[1024];
                float gg = acch[mi][2][r] + accl[mi][2][r] * s_lo + base_r[rb + 2048] + e1[2048] + e2[2048];
                float go = acch[mi][3][r] + accl[mi][3][r] * s_lo + base_r[rb + 3072] + e1[3072] + e2[3072];
                size_t ci = (size_t)row * 1024 + j;
                float cn = sigf(gf) * cr[ci] + sigf(gi) * tanhf(gg);
                cr[ci] = cn;
                float hn = sigf(go) * tanhf(cn);
                hrf[ci] = hn;
                split_f16(hn, oRh[ci], oRl[ci]);
            }
    } else {
        // cell t
#pragma unroll
        for (int mi = 0; mi < 4; mi++)
#pragma unroll
            for (int r = 0; r < 4; r++) {
                int row = m0 + wm * 64 + mi * 16 + lq * 4 + r;
                size_t rb = (size_t)row * 4096 + j;
                const float* e1 = Et_a + (size_t)aidx[row] * 4096 + j;
                float tv = tsv[row];
                float gi = acch[mi][0][r] + accl[mi][0][r] * s_lo + base_t[rb]        + e1[0];
                float gf = acch[mi][1][r] + accl[mi][1][r] * s_lo + base_t[rb + 1024] + e1[1024];
                float gg = acch[mi][2][r] + accl[mi][2][r] * s_lo + base_t[rb + 2048] + e1[2048];
                float go = acch[mi][3][r] + accl[mi][3][r] * s_lo + base_t[rb + 3072] + e1[3072];
                gi = fmaf(tv, wtts[j], gi);        gf = fmaf(tv, wtts[j + 1024], gf);
                gg = fmaf(tv, wtts[j + 2048], gg); go = fmaf(tv, wtts[j + 3072], go);
                size_t ci = (size_t)row * 1024 + j;
                float cn = sigf(gf) * ct[ci] + sigf(gi) * tanhf(gg);
                ct[ci] = cn;
                float hn = sigf(go) * tanhf(cn);
                split_f16(hn, oTh[ci], oTl[ci]);
            }
    }
}

// ---------------- heads: act softmax/argmax (blocks 0..255) + ts_final (256..511) ----------------
__global__ __launch_bounds__(256) void heads(
    const float* __restrict__ haf, const float* __restrict__ actT4, const float* __restrict__ actb,
    float* __restrict__ out_acts, int* __restrict__ aidx, int tact,
    const float* __restrict__ u, const float* __restrict__ w2, const float* __restrict__ b2,
    float* __restrict__ out_ts, float* __restrict__ tsv, int tts)
{
    int blk = blockIdx.x;
    int lane = threadIdx.x & 63, w = threadIdx.x >> 6;
    if (blk < 256) {
        if (tact < 0) return;
        int b = blk * 4 + w;
        float acc = actb[lane];
        const float4* arow = (const float4*)(haf + (size_t)b * 1024);
#pragma unroll 4
        for (int k4 = 0; k4 < 256; k4++) {
            float4 a4 = arow[k4];
            float4 w4 = *(const float4*)(actT4 + ((size_t)k4 * 64 + lane) * 4);
            acc += a4.x * w4.x + a4.y * w4.y + a4.z * w4.z + a4.w * w4.w;
        }
        float v = acc; int idx = lane;
#pragma unroll
        for (int off = 32; off; off >>= 1) {
            float ov = __shfl_xor(v, off);
            int   oi = __shfl_xor(idx, off);
            if (ov > v || (ov == v && oi < idx)) { v = ov; idx = oi; }
        }
        float e = expf(acc - v);
        float s = e;
#pragma unroll
        for (int off = 32; off; off >>= 1) s += __shfl_xor(s, off);
        out_probs_write:
        out_acts[((size_t)b * 64 + tact) * 64 + lane] = e / s;
        if (lane == 0) aidx[b] = idx;
    } else {
        if (tts < 0) return;
        int b = (blk - 256) * 4 + w;
        const float* ur = u + (size_t)b * 512;
        float s = 0.0f;
#pragma unroll
        for (int q = 0; q < 8; q++) s = fmaf(ur[lane + q * 64], w2[lane + q * 64], s);
#pragma unroll
        for (int off = 32; off; off >>= 1) s += __shfl_xor(s, off);
        if (lane == 0) {
            float r = s + b2[0];
            out_ts[b * 64 + tts] = r;
            tsv[b] = r;
        }
    }
}

// ---------------- fp32 GEMM (setup only) ----------------
__global__ __launch_bounds__(256) void gemm_f32(
    const float* __restrict__ A0, const float* __restrict__ W0, float* __restrict__ C0,
    const float* __restrict__ A1, const float* __restrict__ W1, float* __restrict__ C1,
    int lda, int ldw, int ldc, int K, const float* __restrict__ bias, int relu)
{
    const float* Ap = blockIdx.z ? A1 : A0;
    const float* Wp = blockIdx.z ? W1 : W0;
    float*       Cp = blockIdx.z ? C1 : C0;
    __shared__ float As[16][128];
    __shared__ float Bs[16][64];
    const int tid = threadIdx.x;
    const int m0 = blockIdx.x * 128, n0 = blockIdx.y * 64;
    const int tx = tid & 7, ty = tid >> 3;
    const bool wal = (ldw & 3) == 0;
    float acc[4][8];
#pragma unroll
    for (int i = 0; i < 4; i++)
#pragma unroll
        for (int j = 0; j < 8; j++) acc[i][j] = 0.0f;

    for (int k0 = 0; k0 < K; k0 += 16) {
        __syncthreads();
#pragma unroll
        for (int q = 0; q < 2; q++) {
            int t2 = tid + q * 256;
            int kq = t2 & 3, m = t2 >> 2;
            float4 v = *(const float4*)(Ap + (size_t)(m0 + m) * lda + k0 + kq * 4);
            As[kq * 4 + 0][m] = v.x; As[kq * 4 + 1][m] = v.y;
            As[kq * 4 + 2][m] = v.z; As[kq * 4 + 3][m] = v.w;
        }
        {
            int kq = tid & 3, n = tid >> 2;
            const float* src = Wp + (size_t)(n0 + n) * ldw + k0 + kq * 4;
            float4 v;
            if (wal) v = *(const float4*)src;
            else { v.x = src[0]; v.y = src[1]; v.z = src[2]; v.w = src[3]; }
            Bs[kq * 4 + 0][n] = v.x; Bs[kq * 4 + 1][n] = v.y;
            Bs[kq * 4 + 2][n] = v.z; Bs[kq * 4 + 3][n] = v.w;
        }
        __syncthreads();
#pragma unroll
        for (int k = 0; k < 16; k++) {
            float a4[4], b8[8];
            *(float4*)a4 = *(const float4*)&As[k][ty * 4];
            *(float4*)(b8) = *(const float4*)&Bs[k][tx * 8];
            *(float4*)(b8 + 4) = *(const float4*)&Bs[k][tx * 8 + 4];
#pragma unroll
            for (int i = 0; i < 4; i++)
#pragma unroll
                for (int j = 0; j < 8; j++) acc[i][j] = fmaf(a4[i], b8[j], acc[i][j]);
        }
    }
#pragma unroll
    for (int i = 0; i < 4; i++) {
        int m = m0 + ty * 4 + i;
        float vb[8];
#pragma unroll
        for (int j = 0; j < 8; j++) {
            float v = acc[i][j];
            if (bias) v += bias[n0 + tx * 8 + j];
            if (relu) v = fmaxf(v, 0.0f);
            vb[j] = v;
        }
        float* dst = Cp + (size_t)m * ldc + n0 + tx * 8;
        *(float4*)dst = make_float4(vb[0], vb[1], vb[2], vb[3]);
        *(float4*)(dst + 4) = make_float4(vb[4], vb[5], vb[6], vb[7]);
    }
}

// ------------- setup kernels -------------
__global__ void extract_cols(const float* __restrict__ Wih, int ldw, int col0, int ncols,
                             float* __restrict__ E)
{
    int i = blockIdx.x * 256 + threadIdx.x;
    if (i >= ncols * 4096) return;
    int c = i % ncols, j = i / ncols;
    E[(size_t)c * 4096 + j] = Wih[(size_t)j * ldw + col0 + c];
}

__global__ void split_mat_h(const float* __restrict__ X,
                            unsigned short* __restrict__ hi, unsigned short* __restrict__ lo, int n)
{
    int i = blockIdx.x * 256 + threadIdx.x;
    if (i >= n) return;
    split_f16(X[i], hi[i], lo[i]);
}

// pack-transpose: out[((k>>2)*C + c)*4 + (k&3)] = W[c*K + k]
__global__ void transpose_pack(const float* __restrict__ W, int K, int C, float* __restrict__ out)
{
    int i = blockIdx.x * 256 + threadIdx.x;
    if (i >= C * K) return;
    int c = i / K, k = i - c * K;
    out[(((size_t)(k >> 2) * C + c) << 2) + (k & 3)] = W[i];
}

__global__ void init_state(float* __restrict__ cc, unsigned int* __restrict__ hilo,
                           float* __restrict__ tsv, int* __restrict__ aidx, int* __restrict__ ridx)
{
    int i = blockIdx.x * 256 + threadIdx.x;
    if (i < 3 * 1024 * 1024) cc[i] = 0.0f;
    if (i < 6 * 1024 * 1024) hilo[i] = 0u;          // 12M ushort of split state
    if (i < 1024) { tsv[i] = 0.0f; aidx[i] = 63; ridx[i] = 127; }
}

extern "C" void kernel_launch(void* const* d_in, const int* in_sizes, int n_in,
                              void* d_out, int out_size, void* d_ws, size_t ws_size,
                              hipStream_t stream)
{
    const float* z       = (const float*)d_in[0];
    const float* z2t_w   = (const float*)d_in[1];
    const float* z2t_b   = (const float*)d_in[2];
    const float* Wih_a   = (const float*)d_in[3];
    const float* Whh_a   = (const float*)d_in[4];
    const float* b_a     = (const float*)d_in[5];
    const float* Wih_r   = (const float*)d_in[6];
    const float* Whh_r   = (const float*)d_in[7];
    const float* b_r     = (const float*)d_in[8];
    const float* Wih_t   = (const float*)d_in[9];
    const float* Whh_t   = (const float*)d_in[10];
    const float* b_t     = (const float*)d_in[11];
    const float* e2act_w = (const float*)d_in[12];
    const float* e2act_b = (const float*)d_in[13];
    const float* e2res_w = (const float*)d_in[14];
    const float* e2res_b = (const float*)d_in[15];
    const float* e2ts_w1 = (const float*)d_in[16];
    const float* e2ts_b1 = (const float*)d_in[17];
    const float* e2ts_w2 = (const float*)d_in[18];
    const float* e2ts_b2 = (const float*)d_in[19];

    float* out_acts = (float*)d_out;                     // [1024][64][64]
    float* out_ts   = out_acts + (size_t)1024 * 64 * 64; // [1024][64]
    float* out_res  = out_ts + 1024 * 64;                // [1024][64][128]

    float* ws = (float*)d_ws;
    size_t off = 0;
    auto alloc = [&](size_t n) { float* p = ws + off; off += n; return p; };
    float* t_rec  = alloc((size_t)1024 * 512);
    float* base_a = alloc((size_t)1024 * 4096);
    float* base_r = alloc((size_t)1024 * 4096);
    float* base_t = alloc((size_t)1024 * 4096);
    float* Ea     = alloc((size_t)64 * 4096);
    float* Er_a   = alloc((size_t)64 * 4096);
    float* Er_r   = alloc((size_t)128 * 4096);
    float* Et_a   = alloc((size_t)64 * 4096);
    float* wtts   = alloc(4096);
    float* cc     = alloc((size_t)3 * 1024 * 1024);      // ca, cr, ct
    float* ca = cc, * cr = cc + 1048576, * ct = cc + 2097152;
    float* haf    = alloc((size_t)1024 * 1024);
    float* hrf    = alloc((size_t)1024 * 1024);
    float* u      = alloc((size_t)1024 * 512);
    float* tsv    = alloc(1024);
    int*   aidx   = (int*)alloc(1024);
    int*   ridx   = (int*)alloc(1024);
    float* actT4  = alloc((size_t)64 * 1024);
    float* resT4  = alloc((size_t)128 * 1024);
    // ping-pong split state: 12 x 1M ushort = 6M floats
    unsigned short* hilo = (unsigned short*)alloc((size_t)6 * 1024 * 1024);
    const size_t U = 1048576;
    unsigned short* haSp0[2] = {hilo,         hilo + U};
    unsigned short* haSp1[2] = {hilo + 2 * U, hilo + 3 * U};
    unsigned short* hrSp0[2] = {hilo + 4 * U, hilo + 5 * U};
    unsigned short* hrSp1[2] = {hilo + 6 * U, hilo + 7 * U};
    unsigned short* htSp0[2] = {hilo + 8 * U, hilo + 9 * U};
    unsigned short* htSp1[2] = {hilo + 10 * U, hilo + 11 * U};
    // split weights
    unsigned short* WA0 = (unsigned short*)alloc((size_t)2 * 1024 * 1024);
    unsigned short* WA1 = (unsigned short*)alloc((size_t)2 * 1024 * 1024);
    unsigned short* WR0 = (unsigned short*)alloc((size_t)2 * 1024 * 1024);
    unsigned short* WR1 = (unsigned short*)alloc((size_t)2 * 1024 * 1024);
    unsigned short* WT0 = (unsigned short*)alloc((size_t)2 * 1024 * 1024);
    unsigned short* WT1 = (unsigned short*)alloc((size_t)2 * 1024 * 1024);
    unsigned short* W10 = (unsigned short*)alloc((size_t)256 * 1024);
    unsigned short* W11 = (unsigned short*)alloc((size_t)256 * 1024);

    dim3 blk(256);
    init_state<<<(6 * 1024 * 1024 + 255) / 256, blk, 0, stream>>>(cc, (unsigned int*)hilo, tsv, aidx, ridx);

    // t_rec = relu(z @ z2t_w.T + z2t_b)
    gemm_f32<<<dim3(8, 8, 1), blk, 0, stream>>>(z, z2t_w, t_rec, z, z2t_w, t_rec,
                                                256, 256, 512, 256, z2t_b, 1);
    // base_* = t_rec @ Wih_*[:, :512].T + b_*
    gemm_f32<<<dim3(8, 64, 1), blk, 0, stream>>>(t_rec, Wih_a, base_a, t_rec, Wih_a, base_a,
                                                 512, 576, 4096, 512, b_a, 0);
    gemm_f32<<<dim3(8, 64, 1), blk, 0, stream>>>(t_rec, Wih_r, base_r, t_rec, Wih_r, base_r,
                                                 512, 704, 4096, 512, b_r, 0);
    gemm_f32<<<dim3(8, 64, 1), blk, 0, stream>>>(t_rec, Wih_t, base_t, t_rec, Wih_t, base_t,
                                                 512, 577, 4096, 512, b_t, 0);
    // one-hot column tables
    extract_cols<<<(64 * 4096 + 255) / 256, blk, 0, stream>>>(Wih_a, 576, 512, 64, Ea);
    extract_cols<<<(64 * 4096 + 255) / 256, blk, 0, stream>>>(Wih_r, 704, 512, 64, Er_a);
    extract_cols<<<(128 * 4096 + 255) / 256, blk, 0, stream>>>(Wih_r, 704, 576, 128, Er_r);
    extract_cols<<<(64 * 4096 + 255) / 256, blk, 0, stream>>>(Wih_t, 577, 512, 64, Et_a);
    extract_cols<<<(4096 + 255) / 256, blk, 0, stream>>>(Wih_t, 577, 576, 1, wtts);
    // head weight transposes
    transpose_pack<<<(64 * 1024 + 255) / 256, blk, 0, stream>>>(e2act_w, 1024, 64, actT4);
    transpose_pack<<<(128 * 1024 + 255) / 256, blk, 0, stream>>>(e2res_w, 1024, 128, resT4);
    // weight splits (fp16 hi/lo, lo scaled by 2^11)
    split_mat_h<<<(4194304 + 255) / 256, blk, 0, stream>>>(Whh_a, WA0, WA1, 4194304);
    split_mat_h<<<(4194304 + 255) / 256, blk, 0, stream>>>(Whh_r, WR0, WR1, 4194304);
    split_mat_h<<<(4194304 + 255) / 256, blk, 0, stream>>>(Whh_t, WT0, WT1, 4194304);
    split_mat_h<<<(524288 + 255) / 256, blk, 0, stream>>>(e2ts_w1, W10, W11, 524288);

    for (int t = 0; t < 64; t++) {
        int rd = t & 1, wr = rd ^ 1;
        step1<<<832, blk, 0, stream>>>(
            haSp0[rd], haSp1[rd], WA0, WA1, base_a, Ea, aidx,
            ca, haSp0[wr], haSp1[wr], haf,
            htSp0[rd], htSp1[rd], W10, W11, e2ts_b1, u,
            hrf, resT4, e2res_b, out_res, ridx, t, 0);
        heads<<<512, blk, 0, stream>>>(haf, actT4, e2act_b, out_acts, aidx, t,
                                       u, e2ts_w2, e2ts_b2, out_ts, tsv, t - 1);
        step3<<<512, blk, 0, stream>>>(
            hrSp0[rd], hrSp1[rd], WR0, WR1, base_r, Er_a, Er_r, aidx, ridx, tsv,
            cr, hrSp0[wr], hrSp1[wr], hrf,
            htSp0[rd], htSp1[rd], WT0, WT1, base_t, Et_a, wtts,
            ct, htSp0[wr], htSp1[wr]);
    }
    // tail: u(63) from ht(63) (buffers at index 64&1=0), res(63), ts(63)
    step1<<<320, blk, 0, stream>>>(
        haSp0[0], haSp1[0], WA0, WA1, base_a, Ea, aidx,
        ca, haSp0[1], haSp1[1], haf,
        htSp0[0], htSp1[0], W10, W11, e2ts_b1, u,
        hrf, resT4, e2res_b, out_res, ridx, 64, 512);
    heads<<<512, blk, 0, stream>>>(haf, actT4, e2act_b, out_acts, aidx, -1,
                                   u, e2ts_w2, e2ts_b2, out_ts, tsv, 63);
}